// Round 4
// baseline (220.870 us; speedup 1.0000x reference)
//
#include <hip/hip_runtime.h>

#define RANK 128
#define LN_EPS 1e-5f
#define PAD_DEG 64          // padded CSR row capacity (max in-deg ~ Poisson(12.8); P(>=64) ~ 0)

// K1 geometry
#define BT 1024             // K1 block threads
#define CHUNK 12800         // hist bins per block (50 KB LDS)
#define NCH 4               // node ranges (NCH*CHUNK = 51200 >= M)
#define ECH 64              // edge chunks
#define BINS (NCH * CHUNK)
#define NH (ECH * NCH)      // 256 hist blocks
#define NREPACK 6           // 6*1024 = 6144 repack threads
#define NSC3 160            // scan3 blocks (1024 thr, 1 int4/thread covers 640K edges)

#define NSC 160             // scan_bm edge-scan blocks (256 thr, grid-stride)

using short8 = __attribute__((ext_vector_type(8))) short;
using v4f    = __attribute__((ext_vector_type(4))) float;

__device__ inline unsigned short f2bf(float f) {
    unsigned u = __float_as_uint(f);
    unsigned r = (u + 0x7FFF + ((u >> 16) & 1)) >> 16;   // RNE
    return (unsigned short)r;
}

// ---- K1: {LDS-binned src-degree partial histograms | W repack | T3 init | scan3} ----
// scan3: membership dst==first_idx[g] via binary search over boundaries in LDS (no
// scattered reads); matched (~640 edges) -> csr3[g]/curD3[g] + append src to T2.
__global__ __launch_bounds__(BT) void k1(const int* __restrict__ src,
                                         const int* __restrict__ dst, int nE,
                                         unsigned short* __restrict__ psrc,
                                         const float* __restrict__ Ws,
                                         short* __restrict__ Wt,
                                         const int* __restrict__ bnn, int nG,
                                         int* __restrict__ T3, int* __restrict__ cnt3,
                                         int* __restrict__ curD3, int* __restrict__ csr3,
                                         int* __restrict__ T2, int* __restrict__ cnt2) {
    int b = blockIdx.x;
    if (b < NH) {                            // ---- LDS-binned histogram of src ----
        __shared__ int h[CHUNK];
        int c = b & (ECH - 1), nr = b >> 6;  // ECH == 64
        int base = nr * CHUNK;
        for (int i = threadIdx.x; i < CHUNK; i += BT) h[i] = 0;
        __syncthreads();
        int epc = (nE + ECH - 1) / ECH;
        int e0 = c * epc, e1 = min(e0 + epc, nE);
        int tid = threadIdx.x;
        int a0 = min((e0 + 3) & ~3, e1);
        if (tid < a0 - e0) {
            int v = src[e0 + tid] - base;
            if ((unsigned)v < (unsigned)CHUNK) atomicAdd(&h[v], 1);
        }
        int rem = e1 - a0;
        int nv = (rem > 0) ? (rem & ~3) : 0;
        for (int e = a0 + tid * 4; e < a0 + nv; e += BT * 4) {
            int4 v4 = *(const int4*)(src + e);
            int v;
            v = v4.x - base; if ((unsigned)v < (unsigned)CHUNK) atomicAdd(&h[v], 1);
            v = v4.y - base; if ((unsigned)v < (unsigned)CHUNK) atomicAdd(&h[v], 1);
            v = v4.z - base; if ((unsigned)v < (unsigned)CHUNK) atomicAdd(&h[v], 1);
            v = v4.w - base; if ((unsigned)v < (unsigned)CHUNK) atomicAdd(&h[v], 1);
        }
        int t0 = a0 + nv;
        if (tid < e1 - t0) {
            int v = src[t0 + tid] - base;
            if ((unsigned)v < (unsigned)CHUNK) atomicAdd(&h[v], 1);
        }
        __syncthreads();
        unsigned short* o = psrc + (size_t)c * BINS + base;
        for (int i = threadIdx.x; i < CHUNK; i += BT) o[i] = (unsigned short)h[i];
        return;
    }
    if (b < NH + NREPACK) {                  // ---- W repack fp32 -> bf16 MFMA-B layout ----
        int sid = (b - NH) * BT + threadIdx.x;
        if (sid < 3 * 2048) {
            int l = sid >> 11;
            int s = sid & 2047;
            int lane = s & 63, ct = (s >> 6) & 7, k0 = s >> 9;
            int m = lane & 15, quad = lane >> 4;
            const float* W = Ws + (size_t)l * RANK * RANK;
            short* o = Wt + (size_t)l * 16384 + (size_t)s * 8;
#pragma unroll
            for (int j = 0; j < 8; j++)
                o[j] = (short)f2bf(W[(k0 * 32 + quad * 8 + j) * RANK + ct * 16 + m]);
        }
        return;
    }
    if (b == NH + NREPACK) {                 // ---- T3 init ----
        int tid = threadIdx.x;
        if (tid < 64) {
            int lane = tid;
            if (nG <= 64) {
                int v = (lane < nG) ? bnn[lane] : 0;
                int orig = v;
#pragma unroll
                for (int off = 1; off < 64; off <<= 1) {
                    int t = __shfl_up(v, off);
                    if (lane >= off) v += t;
                }
                int excl = v - orig;
                if (lane < nG) T3[lane] = excl;
            } else if (lane == 0) {
                int idx = 0;
                for (int g = 0; g < nG; g++) { T3[g] = idx; idx += bnn[g]; }
            }
            if (lane == 0) *cnt3 = nG;
        }
        return;
    }
    // ---- scan3 blocks ----
    __shared__ int sb[1024];
    for (int i = threadIdx.x; i < 1024; i += BT) sb[i] = 0x7FFFFFFF;
    __syncthreads();
    if (nG <= 64) {
        if (threadIdx.x < 64) {
            int lane = threadIdx.x;
            int v = (lane < nG) ? bnn[lane] : 0;
            int orig = v;
#pragma unroll
            for (int off = 1; off < 64; off <<= 1) {
                int t = __shfl_up(v, off);
                if (lane >= off) v += t;
            }
            int excl = v - orig;
            if (lane < nG) sb[lane] = excl;
        }
    } else if (threadIdx.x == 0) {
        int idx = 0;
        for (int g = 0; g < nG && g < 1024; g++) { sb[g] = idx; idx += bnn[g]; }
    }
    __syncthreads();
    int nGc = (nG < 1024) ? nG : 1024;
    int lane = threadIdx.x & 63;
    int tid = (b - (NH + NREPACK + 1)) * BT + threadIdx.x;
    int NT = NSC3 * BT;
    int n4 = nE >> 2;
    const int4* s4p = (const int4*)src;
    const int4* d4p = (const int4*)dst;

#define PROC3(ss, dd)                                                              \
    {                                                                              \
        int lo_ = 0, hi_ = nGc - 1, g_ = -1;                                       \
        while (lo_ <= hi_) {                                                       \
            int mid_ = (lo_ + hi_) >> 1; int v_ = sb[mid_];                        \
            if (v_ == (dd)) { g_ = mid_; break; }                                  \
            if (v_ < (dd)) lo_ = mid_ + 1; else hi_ = mid_ - 1;                    \
        }                                                                          \
        bool mt_ = (g_ >= 0);                                                      \
        if (mt_) {                                                                 \
            int slot_ = atomicAdd(&curD3[g_], 1);                                  \
            if (slot_ < PAD_DEG) csr3[g_ * PAD_DEG + slot_] = (ss);                \
        }                                                                          \
        unsigned long long mk_ = __ballot(mt_);                                    \
        if (mk_) {                                                                 \
            int ldr_ = __ffsll((long long)mk_) - 1;                                \
            int bs_ = 0;                                                           \
            if (lane == ldr_) bs_ = atomicAdd(cnt2, __popcll(mk_));                \
            bs_ = __shfl(bs_, ldr_);                                               \
            if (mt_) T2[bs_ + __popcll(mk_ & ((1ull << lane) - 1))] = (ss);        \
        }                                                                          \
    }

    for (int i = tid; i < n4; i += NT) {
        int4 d4 = d4p[i];
        int4 s4 = s4p[i];
        PROC3(s4.x, d4.x) PROC3(s4.y, d4.y) PROC3(s4.z, d4.z) PROC3(s4.w, d4.w)
    }
    for (int e = (n4 << 2) + tid; e < nE; e += NT) PROC3(src[e], dst[e])
#undef PROC3
}

// ---- scan_bm: membership via per-block LDS bitmap (65536 bits) built from frontier
// list; matched edges -> node-indexed padded CSR fill; DISC: append srcs (no dedup).
// DISC=1 also carries the partials-reduce -> invout on its first nred blocks. ----
template <int DISC>
__global__ __launch_bounds__(256) void scan_bm(const int* __restrict__ src,
                                               const int* __restrict__ dst, int nE,
                                               const int* __restrict__ Lin,
                                               const int* __restrict__ cntin,
                                               int* __restrict__ cur,
                                               int* __restrict__ csr,
                                               int* __restrict__ Lout,
                                               int* __restrict__ cntout,
                                               const unsigned short* __restrict__ psrc,
                                               float* __restrict__ invout,
                                               int M, int nred) {
    int b = blockIdx.x;
    if (DISC && b < nred) {                  // reduce partial hists -> invout
        int gid = b * 256 + threadIdx.x;
        if (gid < M) {
            int cs = 0;
#pragma unroll 8
            for (int c = 0; c < ECH; c++) cs += psrc[(size_t)c * BINS + gid];
            invout[gid] = rsqrtf(fmaxf((float)cs, 1.0f));
        }
        return;
    }
    __shared__ unsigned lbm[2048];           // 65536 bits >= M
    for (int i = threadIdx.x; i < 2048; i += 256) lbm[i] = 0;
    __syncthreads();
    int nL = *cntin;
    for (int i = threadIdx.x; i < nL; i += 256) {
        int u = Lin[i];
        atomicOr(&lbm[u >> 5], 1u << (u & 31));
    }
    __syncthreads();
    int bb = b - (DISC ? nred : 0);
    int lane = threadIdx.x & 63;
    int tid = bb * 256 + threadIdx.x;
    int NT = NSC * 256;
    int n4 = nE >> 2;
    const int4* s4p = (const int4*)src;
    const int4* d4p = (const int4*)dst;

#define PROCB(ss, dd)                                                              \
    {                                                                              \
        bool mt_ = (lbm[(dd) >> 5] >> ((dd) & 31)) & 1;                            \
        if (mt_) {                                                                 \
            int slot_ = atomicAdd(&cur[dd], 1);                                    \
            if (slot_ < PAD_DEG) csr[(size_t)(dd) * PAD_DEG + slot_] = (ss);       \
        }                                                                          \
        if (DISC) {                                                                \
            unsigned long long mk_ = __ballot(mt_);                                \
            if (mk_) {                                                             \
                int ldr_ = __ffsll((long long)mk_) - 1;                            \
                int bs_ = 0;                                                       \
                if (lane == ldr_) bs_ = atomicAdd(cntout, __popcll(mk_));          \
                bs_ = __shfl(bs_, ldr_);                                           \
                if (mt_) Lout[bs_ + __popcll(mk_ & ((1ull << lane) - 1))] = (ss);  \
            }                                                                      \
        }                                                                          \
    }

    for (int i = tid; i < n4; i += NT) {
        int4 d4 = d4p[i];
        int4 s4 = s4p[i];
        PROCB(s4.x, d4.x) PROCB(s4.y, d4.y) PROCB(s4.z, d4.z) PROCB(s4.w, d4.w)
    }
    for (int e = (n4 << 2) + tid; e < nE; e += NT) PROCB(src[e], dst[e])
#undef PROCB
}

// ---- fused layer: padded-CSR gather (<=64 srcs/row) + bf16 MFMA + invin/bias/LN/ReLU ----
// cin = fill cursors (full in-degree). LAST: csr/cin indexed by tile row (graph id);
// otherwise by node id. FP32IN: fp32 feature rows scaled per-edge by edge_scale.
template <int LAST, int FP32IN>
__global__ __launch_bounds__(256) void layer_fused(const void* __restrict__ FinV,
                                                   const float* __restrict__ edge_scale,
                                                   const int* __restrict__ cin,
                                                   const int* __restrict__ csr,
                                                   const short* __restrict__ Wt,
                                                   const float* __restrict__ invout,
                                                   const float* __restrict__ bias,
                                                   const float* __restrict__ gamma,
                                                   const float* __restrict__ beta,
                                                   const int* __restrict__ list,
                                                   const int* __restrict__ cnt,
                                                   unsigned short* __restrict__ Fout,
                                                   float* __restrict__ out) {
    const unsigned* Fb = (const unsigned*)FinV;
    const float4*  Ff = (const float4*)FinV;
    __shared__ short As[16][136];
    __shared__ float sstat[2][4][16];
    __shared__ float sinv[2][16];
    __shared__ int snode[16];
    int tid = threadIdx.x;
    int w = tid >> 6, lane = tid & 63;
    int seg = lane >> 4, m = lane & 15;
    int n = *cnt;
    int tiles = (n + 15) >> 4;

    float bb[2], gg[2], pp[2];
#pragma unroll
    for (int j = 0; j < 2; j++) {
        int col = (w * 2 + j) * 16 + m;
        bb[j] = bias[col]; gg[j] = gamma[col]; pp[j] = beta[col];
    }

    for (int t = blockIdx.x; t < tiles; t += gridDim.x) {
        int base = t * 16;

        // ---- phase 1: gather 16 rows into LDS ----
        for (int q = 0; q < 4; q++) {
            int rr = w * 4 + q;
            int gr = base + rr;
            float ax[8];
#pragma unroll
            for (int k = 0; k < 8; k++) ax[k] = 0.f;
            int node = -1;
            int cv = 0;
            if (gr < n) {
                node = list[gr];
                int rowi = LAST ? gr : node;
                cv = cin[rowi];
                int nn = min(cv, PAD_DEG);
                int myi = 0;
                if (lane < nn) myi = csr[(size_t)rowi * PAD_DEG + lane];
                int p = 0;
                for (; p + 16 <= nn; p += 16) {
                    if (FP32IN) {
                        float4 fa[4], fb4[4]; float so[4];
#pragma unroll
                        for (int gi = 0; gi < 4; gi++) {
                            int idx = __shfl(myi, p + gi * 4 + seg);
                            so[gi] = edge_scale[idx];
                            const float4* qq = Ff + (size_t)idx * 32 + m * 2;
                            fa[gi] = qq[0]; fb4[gi] = qq[1];
                        }
#pragma unroll
                        for (int gi = 0; gi < 4; gi++) {
                            ax[0] += fa[gi].x * so[gi]; ax[1] += fa[gi].y * so[gi];
                            ax[2] += fa[gi].z * so[gi]; ax[3] += fa[gi].w * so[gi];
                            ax[4] += fb4[gi].x * so[gi]; ax[5] += fb4[gi].y * so[gi];
                            ax[6] += fb4[gi].z * so[gi]; ax[7] += fb4[gi].w * so[gi];
                        }
                    } else {
                        uint4 u[4];
#pragma unroll
                        for (int gi = 0; gi < 4; gi++) {
                            int idx = __shfl(myi, p + gi * 4 + seg);
                            u[gi] = *(const uint4*)(Fb + (size_t)idx * 64 + m * 4);
                        }
#pragma unroll
                        for (int gi = 0; gi < 4; gi++) {
                            ax[0] += __uint_as_float(u[gi].x << 16);
                            ax[1] += __uint_as_float(u[gi].x & 0xFFFF0000u);
                            ax[2] += __uint_as_float(u[gi].y << 16);
                            ax[3] += __uint_as_float(u[gi].y & 0xFFFF0000u);
                            ax[4] += __uint_as_float(u[gi].z << 16);
                            ax[5] += __uint_as_float(u[gi].z & 0xFFFF0000u);
                            ax[6] += __uint_as_float(u[gi].w << 16);
                            ax[7] += __uint_as_float(u[gi].w & 0xFFFF0000u);
                        }
                    }
                }
                for (; p < nn; p += 4) {
                    bool act = (p + seg) < nn;
                    int idx = __shfl(myi, (p + seg) & 63);
                    if (act) {
                        if (FP32IN) {
                            float so = edge_scale[idx];
                            const float4* qq = Ff + (size_t)idx * 32 + m * 2;
                            float4 fa = qq[0], fb4 = qq[1];
                            ax[0] += fa.x * so; ax[1] += fa.y * so;
                            ax[2] += fa.z * so; ax[3] += fa.w * so;
                            ax[4] += fb4.x * so; ax[5] += fb4.y * so;
                            ax[6] += fb4.z * so; ax[7] += fb4.w * so;
                        } else {
                            uint4 u = *(const uint4*)(Fb + (size_t)idx * 64 + m * 4);
                            ax[0] += __uint_as_float(u.x << 16);
                            ax[1] += __uint_as_float(u.x & 0xFFFF0000u);
                            ax[2] += __uint_as_float(u.y << 16);
                            ax[3] += __uint_as_float(u.y & 0xFFFF0000u);
                            ax[4] += __uint_as_float(u.z << 16);
                            ax[5] += __uint_as_float(u.z & 0xFFFF0000u);
                            ax[6] += __uint_as_float(u.w << 16);
                            ax[7] += __uint_as_float(u.w & 0xFFFF0000u);
                        }
                    }
                }
#pragma unroll
                for (int k = 0; k < 8; k++) {
                    ax[k] += __shfl_xor(ax[k], 16);
                    ax[k] += __shfl_xor(ax[k], 32);
                }
            }
            if (seg == 0) {   // lane m holds cols 8m..8m+7 of row rr
                uint4 o;
                o.x = (unsigned)f2bf(ax[0]) | ((unsigned)f2bf(ax[1]) << 16);
                o.y = (unsigned)f2bf(ax[2]) | ((unsigned)f2bf(ax[3]) << 16);
                o.z = (unsigned)f2bf(ax[4]) | ((unsigned)f2bf(ax[5]) << 16);
                o.w = (unsigned)f2bf(ax[6]) | ((unsigned)f2bf(ax[7]) << 16);
                *(uint4*)&As[rr][8 * m] = o;
            }
            if (lane == 0) {
                snode[rr] = node;
                sinv[0][rr] = (gr < n) ? rsqrtf(fmaxf((float)cv, 1.0f)) : 1.f;
                sinv[1][rr] = (!LAST && node >= 0) ? invout[node] : 1.f;
            }
        }
        __syncthreads();

        // ---- phase 2: MFMA (wave w covers cols w*32..w*32+31) ----
        short8 a[4];
#pragma unroll
        for (int k0 = 0; k0 < 4; k0++)
            a[k0] = *(const short8*)&As[m][k0 * 32 + seg * 8];
        v4f acc[2];
        acc[0] = (v4f){0.f, 0.f, 0.f, 0.f};
        acc[1] = (v4f){0.f, 0.f, 0.f, 0.f};
#pragma unroll
        for (int k0 = 0; k0 < 4; k0++) {
#pragma unroll
            for (int j = 0; j < 2; j++) {
                int ct = w * 2 + j;
                short8 b = *(const short8*)(Wt + (size_t)((k0 * 8 + ct) * 64 + lane) * 8);
                acc[j] = __builtin_amdgcn_mfma_f32_16x16x32_bf16(a[k0], b, acc[j], 0, 0, 0);
            }
        }

        float x[4][2];
#pragma unroll
        for (int r = 0; r < 4; r++) {
            int row = seg * 4 + r;
            float iv = sinv[0][row];
            float s = 0.f, sq = 0.f;
#pragma unroll
            for (int j = 0; j < 2; j++) {
                float c = acc[j][r] * iv + bb[j];
                x[r][j] = c;
                s += c; sq += c * c;
            }
#pragma unroll
            for (int off = 1; off < 16; off <<= 1) {
                s  += __shfl_xor(s, off);
                sq += __shfl_xor(sq, off);
            }
            if (m == 0) { sstat[0][w][row] = s; sstat[1][w][row] = sq; }
        }
        __syncthreads();

#pragma unroll
        for (int r = 0; r < 4; r++) {
            int row = seg * 4 + r;
            int gr = base + row;
            if (gr >= n) continue;
            float s  = sstat[0][0][row] + sstat[0][1][row] + sstat[0][2][row] + sstat[0][3][row];
            float sq = sstat[1][0][row] + sstat[1][1][row] + sstat[1][2][row] + sstat[1][3][row];
            float mu = s * (1.0f / RANK);
            float var = sq * (1.0f / RANK) - mu * mu;
            float rs = rsqrtf(var + LN_EPS);
#pragma unroll
            for (int j = 0; j < 2; j++) {
                int col = (w * 2 + j) * 16 + m;
                float y = fmaxf((x[r][j] - mu) * rs * gg[j] + pp[j], 0.f);
                if (LAST) {
                    out[(size_t)gr * RANK + col] = y;
                } else {
                    Fout[(size_t)snode[row] * RANK + col] = f2bf(y * sinv[1][row]);
                }
            }
        }
        __syncthreads();
    }
}

extern "C" void kernel_launch(void* const* d_in, const int* in_sizes, int n_in,
                              void* d_out, int out_size, void* d_ws, size_t ws_size,
                              hipStream_t stream) {
    const float* features = (const float*)d_in[0];
    const int* src = (const int*)d_in[1];
    const int* dst = (const int*)d_in[2];
    const int* bnn = (const int*)d_in[3];
    const float* Ws = (const float*)d_in[4];
    const float* bs = (const float*)d_in[5];
    const float* gammas = (const float*)d_in[6];
    const float* betas = (const float*)d_in[7];
    float* out = (float*)d_out;

    int M  = in_sizes[0] / RANK;   // 50000
    int nE = in_sizes[1];          // 640000
    int nG = in_sizes[3];          // 50
    int Mp  = (M + 63) & ~63;

    char* ws = (char*)d_ws;
    size_t off = 0;
    auto alloc = [&](size_t bytes) {
        void* p = ws + off;
        off += (bytes + 255) & ~(size_t)255;
        return p;
    };
    // zeroed block: curD1 | curD2 | curD3 | cnts
    size_t zInts = (size_t)2 * Mp + 1024 + 64;
    int* zbase = (int*)alloc(zInts * 4);
    int* curD1 = zbase;
    int* curD2 = zbase + Mp;
    int* curD3 = zbase + 2 * (size_t)Mp;
    int* cnts  = zbase + 2 * (size_t)Mp + 1024;
    int* cnt1 = cnts, * cnt2 = cnts + 1, * cnt3 = cnts + 2;

    unsigned short* psrc = (unsigned short*)alloc((size_t)ECH * BINS * 2);  // 6.55 MB
    int*   csr1 = (int*)alloc((size_t)Mp * PAD_DEG * 4);                    // 12.8 MB
    int*   csr2 = (int*)alloc((size_t)Mp * PAD_DEG * 4);                    // 12.8 MB
    int*   csr3 = (int*)alloc((size_t)1024 * PAD_DEG * 4);
    int*   T1   = (int*)alloc((size_t)nE * 4);      // frontier lists (with dups), cap nE
    int*   T2   = (int*)alloc((size_t)nE * 4);
    int*   T3   = (int*)alloc((size_t)1024 * 4);
    short* Wt   = (short*)alloc((size_t)3 * 16384 * 2);
    short* F1   = (short*)alloc((size_t)M * RANK * 2);
    short* F2   = (short*)alloc((size_t)M * RANK * 2);
    float* invout = (float*)alloc((size_t)M * 4);

    hipMemsetAsync(zbase, 0, zInts * 4, stream);

    // K1: hist partials + W repack + T3 init + scan3 (fills csr3, discovers T2)
    k1<<<NH + NREPACK + 1 + NSC3, BT, 0, stream>>>(src, dst, nE, psrc, Ws, Wt, bnn, nG,
                                                   T3, cnt3, curD3, csr3, T2, cnt2);
    int nred = (M + 255) / 256;
    // K2: reduce->invout on first nred blocks; scan2 (LDS bitmap of T2, fills csr2, discovers T1)
    scan_bm<1><<<nred + NSC, 256, 0, stream>>>(src, dst, nE, T2, cnt2, curD2, csr2,
                                               T1, cnt1, psrc, invout, M, nred);
    // K3: scan1 (LDS bitmap of T1, fills csr1)
    scan_bm<0><<<NSC, 256, 0, stream>>>(src, dst, nE, T1, cnt1, curD1, csr1,
                                        nullptr, nullptr, nullptr, nullptr, M, 0);
    // fused layers; L1 reads fp32 features with per-edge invout scale
    layer_fused<0, 1><<<512, 256, 0, stream>>>(features, invout, curD1, csr1, Wt,
                                               invout, bs, gammas, betas,
                                               T1, cnt1, (unsigned short*)F1, nullptr);
    layer_fused<0, 0><<<64, 256, 0, stream>>>(F1, nullptr, curD2, csr2, Wt + 16384,
                                              invout, bs + RANK, gammas + RANK, betas + RANK,
                                              T2, cnt2, (unsigned short*)F2, nullptr);
    layer_fused<1, 0><<<(nG + 15) / 16, 256, 0, stream>>>(F2, nullptr, curD3, csr3, Wt + 32768,
                                                          invout, bs + 2 * RANK,
                                                          gammas + 2 * RANK, betas + 2 * RANK,
                                                          T3, cnt3, nullptr, out);
}

// Round 6
// 209.272 us; speedup vs baseline: 1.0554x; 1.0554x over previous
//
#include <hip/hip_runtime.h>

#define RANK 128
#define LN_EPS 1e-5f
#define PAD_DEG 64          // padded CSR row capacity (max in-deg ~ Poisson(12.8); P(>=64) ~ 0)

// K1 geometry
#define BT 1024             // K1 block threads
#define CHUNK 12800         // hist bins per block (50 KB LDS)
#define NCH 4               // node ranges (NCH*CHUNK = 51200 >= M)
#define ECH 64              // edge chunks
#define BINS (NCH * CHUNK)
#define NH (ECH * NCH)      // 256 hist blocks
#define NREPACK 6           // 6*1024 = 6144 repack threads
#define NSC3 160            // scan3 blocks (1024 thr, 1 int4/thread covers 640K edges)

using short8 = __attribute__((ext_vector_type(8))) short;
using v4f    = __attribute__((ext_vector_type(4))) float;

__device__ inline unsigned short f2bf(float f) {
    unsigned u = __float_as_uint(f);
    unsigned r = (u + 0x7FFF + ((u >> 16) & 1)) >> 16;   // RNE
    return (unsigned short)r;
}

// ---- K1: {LDS-binned src-degree partial histograms | W repack | T3 init | scan3} ----
// scan3: membership dst==first_idx[g] via binary search over boundaries in LDS (no
// scattered reads); matched (~640 edges) -> csr3[g]/curD3[g] + append src to T2.
__global__ __launch_bounds__(BT) void k1(const int* __restrict__ src,
                                         const int* __restrict__ dst, int nE,
                                         unsigned short* __restrict__ psrc,
                                         const float* __restrict__ Ws,
                                         short* __restrict__ Wt,
                                         const int* __restrict__ bnn, int nG,
                                         int* __restrict__ T3, int* __restrict__ cnt3,
                                         int* __restrict__ curD3, int* __restrict__ csr3,
                                         int* __restrict__ T2, int* __restrict__ cnt2) {
    int b = blockIdx.x;
    if (b < NH) {                            // ---- LDS-binned histogram of src ----
        __shared__ int h[CHUNK];
        int c = b & (ECH - 1), nr = b >> 6;  // ECH == 64
        int base = nr * CHUNK;
        for (int i = threadIdx.x; i < CHUNK; i += BT) h[i] = 0;
        __syncthreads();
        int epc = (nE + ECH - 1) / ECH;
        int e0 = c * epc, e1 = min(e0 + epc, nE);
        int tid = threadIdx.x;
        int a0 = min((e0 + 3) & ~3, e1);
        if (tid < a0 - e0) {
            int v = src[e0 + tid] - base;
            if ((unsigned)v < (unsigned)CHUNK) atomicAdd(&h[v], 1);
        }
        int rem = e1 - a0;
        int nv = (rem > 0) ? (rem & ~3) : 0;
        for (int e = a0 + tid * 4; e < a0 + nv; e += BT * 4) {
            int4 v4 = *(const int4*)(src + e);
            int v;
            v = v4.x - base; if ((unsigned)v < (unsigned)CHUNK) atomicAdd(&h[v], 1);
            v = v4.y - base; if ((unsigned)v < (unsigned)CHUNK) atomicAdd(&h[v], 1);
            v = v4.z - base; if ((unsigned)v < (unsigned)CHUNK) atomicAdd(&h[v], 1);
            v = v4.w - base; if ((unsigned)v < (unsigned)CHUNK) atomicAdd(&h[v], 1);
        }
        int t0 = a0 + nv;
        if (tid < e1 - t0) {
            int v = src[t0 + tid] - base;
            if ((unsigned)v < (unsigned)CHUNK) atomicAdd(&h[v], 1);
        }
        __syncthreads();
        unsigned short* o = psrc + (size_t)c * BINS + base;
        for (int i = threadIdx.x; i < CHUNK; i += BT) o[i] = (unsigned short)h[i];
        return;
    }
    if (b < NH + NREPACK) {                  // ---- W repack fp32 -> bf16 MFMA-B layout ----
        int sid = (b - NH) * BT + threadIdx.x;
        if (sid < 3 * 2048) {
            int l = sid >> 11;
            int s = sid & 2047;
            int lane = s & 63, ct = (s >> 6) & 7, k0 = s >> 9;
            int m = lane & 15, quad = lane >> 4;
            const float* W = Ws + (size_t)l * RANK * RANK;
            short* o = Wt + (size_t)l * 16384 + (size_t)s * 8;
#pragma unroll
            for (int j = 0; j < 8; j++)
                o[j] = (short)f2bf(W[(k0 * 32 + quad * 8 + j) * RANK + ct * 16 + m]);
        }
        return;
    }
    if (b == NH + NREPACK) {                 // ---- T3 init ----
        int tid = threadIdx.x;
        if (tid < 64) {
            int lane = tid;
            if (nG <= 64) {
                int v = (lane < nG) ? bnn[lane] : 0;
                int orig = v;
#pragma unroll
                for (int off = 1; off < 64; off <<= 1) {
                    int t = __shfl_up(v, off);
                    if (lane >= off) v += t;
                }
                int excl = v - orig;
                if (lane < nG) T3[lane] = excl;
            } else if (lane == 0) {
                int idx = 0;
                for (int g = 0; g < nG; g++) { T3[g] = idx; idx += bnn[g]; }
            }
            if (lane == 0) *cnt3 = nG;
        }
        return;
    }
    // ---- scan3 blocks ----
    __shared__ int sb[1024];
    for (int i = threadIdx.x; i < 1024; i += BT) sb[i] = 0x7FFFFFFF;
    __syncthreads();
    if (nG <= 64) {
        if (threadIdx.x < 64) {
            int lane = threadIdx.x;
            int v = (lane < nG) ? bnn[lane] : 0;
            int orig = v;
#pragma unroll
            for (int off = 1; off < 64; off <<= 1) {
                int t = __shfl_up(v, off);
                if (lane >= off) v += t;
            }
            int excl = v - orig;
            if (lane < nG) sb[lane] = excl;
        }
    } else if (threadIdx.x == 0) {
        int idx = 0;
        for (int g = 0; g < nG && g < 1024; g++) { sb[g] = idx; idx += bnn[g]; }
    }
    __syncthreads();
    int nGc = (nG < 1024) ? nG : 1024;
    int lane = threadIdx.x & 63;
    int tid = (b - (NH + NREPACK + 1)) * BT + threadIdx.x;
    int NT = NSC3 * BT;
    int n4 = nE >> 2;
    const int4* s4p = (const int4*)src;
    const int4* d4p = (const int4*)dst;

#define PROC3(ss, dd)                                                              \
    {                                                                              \
        int lo_ = 0, hi_ = nGc - 1, g_ = -1;                                       \
        while (lo_ <= hi_) {                                                       \
            int mid_ = (lo_ + hi_) >> 1; int v_ = sb[mid_];                        \
            if (v_ == (dd)) { g_ = mid_; break; }                                  \
            if (v_ < (dd)) lo_ = mid_ + 1; else hi_ = mid_ - 1;                    \
        }                                                                          \
        bool mt_ = (g_ >= 0);                                                      \
        if (mt_) {                                                                 \
            int slot_ = atomicAdd(&curD3[g_], 1);                                  \
            if (slot_ < PAD_DEG) csr3[g_ * PAD_DEG + slot_] = (ss);                \
        }                                                                          \
        unsigned long long mk_ = __ballot(mt_);                                    \
        if (mk_) {                                                                 \
            int ldr_ = __ffsll((long long)mk_) - 1;                                \
            int bs_ = 0;                                                           \
            if (lane == ldr_) bs_ = atomicAdd(cnt2, __popcll(mk_));                \
            bs_ = __shfl(bs_, ldr_);                                               \
            if (mt_) T2[bs_ + __popcll(mk_ & ((1ull << lane) - 1))] = (ss);        \
        }                                                                          \
    }

    for (int i = tid; i < n4; i += NT) {
        int4 d4 = d4p[i];
        int4 s4 = s4p[i];
        PROC3(s4.x, d4.x) PROC3(s4.y, d4.y) PROC3(s4.z, d4.z) PROC3(s4.w, d4.w)
    }
    for (int e = (n4 << 2) + tid; e < nE; e += NT) PROC3(src[e], dst[e])
#undef PROC3
}

// ---- scan_bm: membership via per-block LDS bitmap (65536 bits) built from frontier
// list; matched edges -> node-indexed padded CSR fill; DISC: append srcs (no dedup).
// 1024-thread blocks, 1 int4/thread, branchless load phase (k1-scan3-proven shape).
// DISC=1 also carries the partials-reduce -> invout on its first nred blocks. ----
template <int DISC>
__global__ __launch_bounds__(1024) void scan_bm(const int* __restrict__ src,
                                                const int* __restrict__ dst, int nE,
                                                const int* __restrict__ Lin,
                                                const int* __restrict__ cntin,
                                                int* __restrict__ cur,
                                                int* __restrict__ csr,
                                                int* __restrict__ Lout,
                                                int* __restrict__ cntout,
                                                const unsigned short* __restrict__ psrc,
                                                float* __restrict__ invout,
                                                int M, int nred) {
    int b = blockIdx.x;
    if (DISC && b < nred) {                  // reduce partial hists -> invout
        int gid = b * 1024 + threadIdx.x;
        if (gid < M) {
            int cs = 0;
#pragma unroll 8
            for (int c = 0; c < ECH; c++) cs += psrc[(size_t)c * BINS + gid];
            invout[gid] = rsqrtf(fmaxf((float)cs, 1.0f));
        }
        return;
    }
    __shared__ unsigned lbm[2048];           // 65536 bits >= M
    for (int i = threadIdx.x; i < 2048; i += 1024) lbm[i] = 0;
    __syncthreads();
    int nL = *cntin;
    for (int i = threadIdx.x; i < nL; i += 1024) {
        int u = Lin[i];
        atomicOr(&lbm[u >> 5], 1u << (u & 31));
    }
    __syncthreads();
    int bb = b - (DISC ? nred : 0);
    int lane = threadIdx.x & 63;
    int tid = bb * 1024 + threadIdx.x;
    int n4 = nE >> 2;

    // branchless load phase: 2 coalesced int4 loads issued unconditionally
    int4 d4 = {0, 0, 0, 0}, s4 = {0, 0, 0, 0};
    bool in = tid < n4;
    if (in) {
        d4 = ((const int4*)dst)[tid];
        s4 = ((const int4*)src)[tid];
    }

#define PROCB(ss, dd)                                                              \
    {                                                                              \
        bool mt_ = in && ((lbm[(dd) >> 5] >> ((dd) & 31)) & 1);                    \
        if (mt_) {                                                                 \
            int slot_ = atomicAdd(&cur[dd], 1);                                    \
            if (slot_ < PAD_DEG) csr[(size_t)(dd) * PAD_DEG + slot_] = (ss);       \
        }                                                                          \
        if (DISC) {                                                                \
            unsigned long long mk_ = __ballot(mt_);                                \
            if (mk_) {                                                             \
                int ldr_ = __ffsll((long long)mk_) - 1;                            \
                int bs_ = 0;                                                       \
                if (lane == ldr_) bs_ = atomicAdd(cntout, __popcll(mk_));          \
                bs_ = __shfl(bs_, ldr_);                                           \
                if (mt_) Lout[bs_ + __popcll(mk_ & ((1ull << lane) - 1))] = (ss);  \
            }                                                                      \
        }                                                                          \
    }

    PROCB(s4.x, d4.x) PROCB(s4.y, d4.y) PROCB(s4.z, d4.z) PROCB(s4.w, d4.w)

    // tail edges (nE % 4)
    {
        int e = (n4 << 2) + tid;
        bool tin = e < nE;
        int st = 0, dt = 0;
        if (tin) { st = src[e]; dt = dst[e]; }
        bool save_in = in;
        in = tin;
        PROCB(st, dt)
        in = save_in;
    }
#undef PROCB
}

// ---- fused layer: padded-CSR gather (<=64 srcs/row) + bf16 MFMA + invin/bias/LN/ReLU ----
// cin = fill cursors (full in-degree). LAST: csr/cin indexed by tile row (graph id);
// otherwise by node id. FP32IN: fp32 feature rows scaled per-edge by edge_scale.
template <int LAST, int FP32IN>
__global__ __launch_bounds__(256) void layer_fused(const void* __restrict__ FinV,
                                                   const float* __restrict__ edge_scale,
                                                   const int* __restrict__ cin,
                                                   const int* __restrict__ csr,
                                                   const short* __restrict__ Wt,
                                                   const float* __restrict__ invout,
                                                   const float* __restrict__ bias,
                                                   const float* __restrict__ gamma,
                                                   const float* __restrict__ beta,
                                                   const int* __restrict__ list,
                                                   const int* __restrict__ cnt,
                                                   unsigned short* __restrict__ Fout,
                                                   float* __restrict__ out) {
    const unsigned* Fb = (const unsigned*)FinV;
    const float4*  Ff = (const float4*)FinV;
    __shared__ short As[16][136];
    __shared__ float sstat[2][4][16];
    __shared__ float sinv[2][16];
    __shared__ int snode[16];
    int tid = threadIdx.x;
    int w = tid >> 6, lane = tid & 63;
    int seg = lane >> 4, m = lane & 15;
    int n = *cnt;
    int tiles = (n + 15) >> 4;

    float bb[2], gg[2], pp[2];
#pragma unroll
    for (int j = 0; j < 2; j++) {
        int col = (w * 2 + j) * 16 + m;
        bb[j] = bias[col]; gg[j] = gamma[col]; pp[j] = beta[col];
    }

    for (int t = blockIdx.x; t < tiles; t += gridDim.x) {
        int base = t * 16;

        // ---- phase 1: gather 16 rows into LDS ----
        for (int q = 0; q < 4; q++) {
            int rr = w * 4 + q;
            int gr = base + rr;
            float ax[8];
#pragma unroll
            for (int k = 0; k < 8; k++) ax[k] = 0.f;
            int node = -1;
            int cv = 0;
            if (gr < n) {
                node = list[gr];
                int rowi = LAST ? gr : node;
                cv = cin[rowi];
                int nn = min(cv, PAD_DEG);
                int myi = 0;
                if (lane < nn) myi = csr[(size_t)rowi * PAD_DEG + lane];
                int p = 0;
                for (; p + 16 <= nn; p += 16) {
                    if (FP32IN) {
                        float4 fa[4], fb4[4]; float so[4];
#pragma unroll
                        for (int gi = 0; gi < 4; gi++) {
                            int idx = __shfl(myi, p + gi * 4 + seg);
                            so[gi] = edge_scale[idx];
                            const float4* qq = Ff + (size_t)idx * 32 + m * 2;
                            fa[gi] = qq[0]; fb4[gi] = qq[1];
                        }
#pragma unroll
                        for (int gi = 0; gi < 4; gi++) {
                            ax[0] += fa[gi].x * so[gi]; ax[1] += fa[gi].y * so[gi];
                            ax[2] += fa[gi].z * so[gi]; ax[3] += fa[gi].w * so[gi];
                            ax[4] += fb4[gi].x * so[gi]; ax[5] += fb4[gi].y * so[gi];
                            ax[6] += fb4[gi].z * so[gi]; ax[7] += fb4[gi].w * so[gi];
                        }
                    } else {
                        uint4 u[4];
#pragma unroll
                        for (int gi = 0; gi < 4; gi++) {
                            int idx = __shfl(myi, p + gi * 4 + seg);
                            u[gi] = *(const uint4*)(Fb + (size_t)idx * 64 + m * 4);
                        }
#pragma unroll
                        for (int gi = 0; gi < 4; gi++) {
                            ax[0] += __uint_as_float(u[gi].x << 16);
                            ax[1] += __uint_as_float(u[gi].x & 0xFFFF0000u);
                            ax[2] += __uint_as_float(u[gi].y << 16);
                            ax[3] += __uint_as_float(u[gi].y & 0xFFFF0000u);
                            ax[4] += __uint_as_float(u[gi].z << 16);
                            ax[5] += __uint_as_float(u[gi].z & 0xFFFF0000u);
                            ax[6] += __uint_as_float(u[gi].w << 16);
                            ax[7] += __uint_as_float(u[gi].w & 0xFFFF0000u);
                        }
                    }
                }
                for (; p < nn; p += 4) {
                    bool act = (p + seg) < nn;
                    int idx = __shfl(myi, (p + seg) & 63);
                    if (act) {
                        if (FP32IN) {
                            float so = edge_scale[idx];
                            const float4* qq = Ff + (size_t)idx * 32 + m * 2;
                            float4 fa = qq[0], fb4 = qq[1];
                            ax[0] += fa.x * so; ax[1] += fa.y * so;
                            ax[2] += fa.z * so; ax[3] += fa.w * so;
                            ax[4] += fb4.x * so; ax[5] += fb4.y * so;
                            ax[6] += fb4.z * so; ax[7] += fb4.w * so;
                        } else {
                            uint4 u = *(const uint4*)(Fb + (size_t)idx * 64 + m * 4);
                            ax[0] += __uint_as_float(u.x << 16);
                            ax[1] += __uint_as_float(u.x & 0xFFFF0000u);
                            ax[2] += __uint_as_float(u.y << 16);
                            ax[3] += __uint_as_float(u.y & 0xFFFF0000u);
                            ax[4] += __uint_as_float(u.z << 16);
                            ax[5] += __uint_as_float(u.z & 0xFFFF0000u);
                            ax[6] += __uint_as_float(u.w << 16);
                            ax[7] += __uint_as_float(u.w & 0xFFFF0000u);
                        }
                    }
                }
#pragma unroll
                for (int k = 0; k < 8; k++) {
                    ax[k] += __shfl_xor(ax[k], 16);
                    ax[k] += __shfl_xor(ax[k], 32);
                }
            }
            if (seg == 0) {   // lane m holds cols 8m..8m+7 of row rr
                uint4 o;
                o.x = (unsigned)f2bf(ax[0]) | ((unsigned)f2bf(ax[1]) << 16);
                o.y = (unsigned)f2bf(ax[2]) | ((unsigned)f2bf(ax[3]) << 16);
                o.z = (unsigned)f2bf(ax[4]) | ((unsigned)f2bf(ax[5]) << 16);
                o.w = (unsigned)f2bf(ax[6]) | ((unsigned)f2bf(ax[7]) << 16);
                *(uint4*)&As[rr][8 * m] = o;
            }
            if (lane == 0) {
                snode[rr] = node;
                sinv[0][rr] = (gr < n) ? rsqrtf(fmaxf((float)cv, 1.0f)) : 1.f;
                sinv[1][rr] = (!LAST && node >= 0) ? invout[node] : 1.f;
            }
        }
        __syncthreads();

        // ---- phase 2: MFMA (wave w covers cols w*32..w*32+31) ----
        short8 a[4];
#pragma unroll
        for (int k0 = 0; k0 < 4; k0++)
            a[k0] = *(const short8*)&As[m][k0 * 32 + seg * 8];
        v4f acc[2];
        acc[0] = (v4f){0.f, 0.f, 0.f, 0.f};
        acc[1] = (v4f){0.f, 0.f, 0.f, 0.f};
#pragma unroll
        for (int k0 = 0; k0 < 4; k0++) {
#pragma unroll
            for (int j = 0; j < 2; j++) {
                int ct = w * 2 + j;
                short8 b = *(const short8*)(Wt + (size_t)((k0 * 8 + ct) * 64 + lane) * 8);
                acc[j] = __builtin_amdgcn_mfma_f32_16x16x32_bf16(a[k0], b, acc[j], 0, 0, 0);
            }
        }

        float x[4][2];
#pragma unroll
        for (int r = 0; r < 4; r++) {
            int row = seg * 4 + r;
            float iv = sinv[0][row];
            float s = 0.f, sq = 0.f;
#pragma unroll
            for (int j = 0; j < 2; j++) {
                float c = acc[j][r] * iv + bb[j];
                x[r][j] = c;
                s += c; sq += c * c;
            }
#pragma unroll
            for (int off = 1; off < 16; off <<= 1) {
                s  += __shfl_xor(s, off);
                sq += __shfl_xor(sq, off);
            }
            if (m == 0) { sstat[0][w][row] = s; sstat[1][w][row] = sq; }
        }
        __syncthreads();

#pragma unroll
        for (int r = 0; r < 4; r++) {
            int row = seg * 4 + r;
            int gr = base + row;
            if (gr >= n) continue;
            float s  = sstat[0][0][row] + sstat[0][1][row] + sstat[0][2][row] + sstat[0][3][row];
            float sq = sstat[1][0][row] + sstat[1][1][row] + sstat[1][2][row] + sstat[1][3][row];
            float mu = s * (1.0f / RANK);
            float var = sq * (1.0f / RANK) - mu * mu;
            float rs = rsqrtf(var + LN_EPS);
#pragma unroll
            for (int j = 0; j < 2; j++) {
                int col = (w * 2 + j) * 16 + m;
                float y = fmaxf((x[r][j] - mu) * rs * gg[j] + pp[j], 0.f);
                if (LAST) {
                    out[(size_t)gr * RANK + col] = y;
                } else {
                    Fout[(size_t)snode[row] * RANK + col] = f2bf(y * sinv[1][row]);
                }
            }
        }
        __syncthreads();
    }
}

extern "C" void kernel_launch(void* const* d_in, const int* in_sizes, int n_in,
                              void* d_out, int out_size, void* d_ws, size_t ws_size,
                              hipStream_t stream) {
    const float* features = (const float*)d_in[0];
    const int* src = (const int*)d_in[1];
    const int* dst = (const int*)d_in[2];
    const int* bnn = (const int*)d_in[3];
    const float* Ws = (const float*)d_in[4];
    const float* bs = (const float*)d_in[5];
    const float* gammas = (const float*)d_in[6];
    const float* betas = (const float*)d_in[7];
    float* out = (float*)d_out;

    int M  = in_sizes[0] / RANK;   // 50000
    int nE = in_sizes[1];          // 640000
    int nG = in_sizes[3];          // 50
    int Mp  = (M + 63) & ~63;

    char* ws = (char*)d_ws;
    size_t off = 0;
    auto alloc = [&](size_t bytes) {
        void* p = ws + off;
        off += (bytes + 255) & ~(size_t)255;
        return p;
    };
    // zeroed block: curD1 | curD2 | curD3 | cnts
    size_t zInts = (size_t)2 * Mp + 1024 + 64;
    int* zbase = (int*)alloc(zInts * 4);
    int* curD1 = zbase;
    int* curD2 = zbase + Mp;
    int* curD3 = zbase + 2 * (size_t)Mp;
    int* cnts  = zbase + 2 * (size_t)Mp + 1024;
    int* cnt1 = cnts, * cnt2 = cnts + 1, * cnt3 = cnts + 2;

    unsigned short* psrc = (unsigned short*)alloc((size_t)ECH * BINS * 2);  // 6.55 MB
    int*   csr1 = (int*)alloc((size_t)Mp * PAD_DEG * 4);                    // 12.8 MB
    int*   csr2 = (int*)alloc((size_t)Mp * PAD_DEG * 4);                    // 12.8 MB
    int*   csr3 = (int*)alloc((size_t)1024 * PAD_DEG * 4);
    int*   T1   = (int*)alloc((size_t)nE * 4);      // frontier lists (with dups), cap nE
    int*   T2   = (int*)alloc((size_t)nE * 4);
    int*   T3   = (int*)alloc((size_t)1024 * 4);
    short* Wt   = (short*)alloc((size_t)3 * 16384 * 2);
    short* F1   = (short*)alloc((size_t)M * RANK * 2);
    short* F2   = (short*)alloc((size_t)M * RANK * 2);
    float* invout = (float*)alloc((size_t)M * 4);

    hipMemsetAsync(zbase, 0, zInts * 4, stream);

    // K1: hist partials + W repack + T3 init + scan3 (fills csr3, discovers T2)
    k1<<<NH + NREPACK + 1 + NSC3, BT, 0, stream>>>(src, dst, nE, psrc, Ws, Wt, bnn, nG,
                                                   T3, cnt3, curD3, csr3, T2, cnt2);
    int n4   = nE >> 2;
    int nscb = (n4 + 1023) / 1024;     // 1 int4 per thread at 1024-thread blocks
    int nred = (M + 1023) / 1024;
    // K2: reduce->invout on first nred blocks; scan2 (LDS bitmap of T2, fills csr2, discovers T1)
    scan_bm<1><<<nred + nscb, 1024, 0, stream>>>(src, dst, nE, T2, cnt2, curD2, csr2,
                                                 T1, cnt1, psrc, invout, M, nred);
    // K3: scan1 (LDS bitmap of T1, fills csr1)
    scan_bm<0><<<nscb, 1024, 0, stream>>>(src, dst, nE, T1, cnt1, curD1, csr1,
                                          nullptr, nullptr, nullptr, nullptr, M, 0);
    // fused layers; L1 reads fp32 features with per-edge invout scale
    layer_fused<0, 1><<<512, 256, 0, stream>>>(features, invout, curD1, csr1, Wt,
                                               invout, bs, gammas, betas,
                                               T1, cnt1, (unsigned short*)F1, nullptr);
    layer_fused<0, 0><<<64, 256, 0, stream>>>(F1, nullptr, curD2, csr2, Wt + 16384,
                                              invout, bs + RANK, gammas + RANK, betas + RANK,
                                              T2, cnt2, (unsigned short*)F2, nullptr);
    layer_fused<1, 0><<<(nG + 15) / 16, 256, 0, stream>>>(F2, nullptr, curD3, csr3, Wt + 32768,
                                                          invout, bs + 2 * RANK,
                                                          gammas + 2 * RANK, betas + 2 * RANK,
                                                          T3, cnt3, nullptr, out);
}

// Round 7
// 170.024 us; speedup vs baseline: 1.2991x; 1.2308x over previous
//
#include <hip/hip_runtime.h>

#define RANK 128
#define LN_EPS 1e-5f

// CSR-build geometry (round-0 proven: M=50000, nE=640000)
#define NCH 4
#define CHUNK 12800            // NCH*CHUNK = 51200 >= M ; LDS = 50 KB
#define BINS (NCH * CHUNK)
#define ECH 64                 // edge chunks
#define BT 1024                // threads per CSR-build block

using short8 = __attribute__((ext_vector_type(8))) short;
using v4f    = __attribute__((ext_vector_type(4))) float;

__device__ inline unsigned short f2bf(float f) {
    unsigned u = __float_as_uint(f);
    unsigned r = (u + 0x7FFF + ((u >> 16) & 1)) >> 16;   // RNE
    return (unsigned short)r;
}

// ---- partial histograms (u16, no global atomics) + W repack + T3 init on spare blocks ----
__global__ __launch_bounds__(BT) void hist_part(const int* __restrict__ src,
                                                const int* __restrict__ dst,
                                                unsigned short* __restrict__ pdst,
                                                unsigned short* __restrict__ psrc,
                                                const float* __restrict__ Ws,
                                                short* __restrict__ Wt, int nE,
                                                const int* __restrict__ bnn, int nG,
                                                int* __restrict__ T3, int* __restrict__ cnt3) {
    int c = blockIdx.x, n = blockIdx.y, z = blockIdx.z;
    if (c == ECH) {   // spare blocks: (n,z) -> 8 blocks x 1024 threads
        int sid = (n + 4 * z) * BT + threadIdx.x;
        if (sid < 3 * 2048) {                // W repack fp32 -> bf16 MFMA-B layout
            int l = sid >> 11;
            int s = sid & 2047;
            int lane = s & 63, ct = (s >> 6) & 7, k0 = s >> 9;
            int m = lane & 15, quad = lane >> 4;
            const float* W = Ws + (size_t)l * RANK * RANK;
            short* o = Wt + (size_t)l * 16384 + (size_t)s * 8;
#pragma unroll
            for (int j = 0; j < 8; j++)
                o[j] = (short)f2bf(W[(k0 * 32 + quad * 8 + j) * RANK + ct * 16 + m]);
        } else if (sid >= 6144 && sid < 6208) {   // T3 init (one wave)
            int lane = sid - 6144;
            if (nG <= 64) {
                int v = (lane < nG) ? bnn[lane] : 0;
                int orig = v;
#pragma unroll
                for (int off = 1; off < 64; off <<= 1) {
                    int t = __shfl_up(v, off);
                    if (lane >= off) v += t;
                }
                int excl = v - orig;
                if (lane < nG) T3[lane] = excl;
                if (lane == 0) *cnt3 = nG;
            } else if (lane == 0) {
                int idx = 0;
                for (int g = 0; g < nG; g++) { T3[g] = idx; idx += bnn[g]; }
                *cnt3 = nG;
            }
        }
        return;
    }
    __shared__ int h[CHUNK];
    const int* arr = z ? src : dst;
    unsigned short* pout = z ? psrc : pdst;
    int base = n * CHUNK;
    for (int i = threadIdx.x; i < CHUNK; i += BT) h[i] = 0;
    __syncthreads();
    int epc = (nE + ECH - 1) / ECH;
    int e0 = c * epc, e1 = min(e0 + epc, nE);
    int tid = threadIdx.x;
    int a0 = min((e0 + 3) & ~3, e1);
    if (tid < a0 - e0) {
        int v = arr[e0 + tid] - base;
        if ((unsigned)v < (unsigned)CHUNK) atomicAdd(&h[v], 1);
    }
    int rem = e1 - a0;
    int nv = (rem > 0) ? (rem & ~3) : 0;
    for (int e = a0 + tid * 4; e < a0 + nv; e += BT * 4) {
        int4 v4 = *(const int4*)(arr + e);
        int v;
        v = v4.x - base; if ((unsigned)v < (unsigned)CHUNK) atomicAdd(&h[v], 1);
        v = v4.y - base; if ((unsigned)v < (unsigned)CHUNK) atomicAdd(&h[v], 1);
        v = v4.z - base; if ((unsigned)v < (unsigned)CHUNK) atomicAdd(&h[v], 1);
        v = v4.w - base; if ((unsigned)v < (unsigned)CHUNK) atomicAdd(&h[v], 1);
    }
    int t0 = a0 + nv;
    if (tid < e1 - t0) {
        int v = arr[t0 + tid] - base;
        if ((unsigned)v < (unsigned)CHUNK) atomicAdd(&h[v], 1);
    }
    __syncthreads();
    unsigned short* o = pout + (size_t)c * BINS + base;
    for (int i = threadIdx.x; i < CHUNK; i += BT) o[i] = (unsigned short)h[i];
}

// ------- reduce u16 partials -> counts/invin/invout + in-block inclusive scan -------
__global__ __launch_bounds__(256) void reduce_scan1(const unsigned short* __restrict__ pdst,
                                                    const unsigned short* __restrict__ psrc,
                                                    int* __restrict__ counts,
                                                    float* __restrict__ invin,
                                                    float* __restrict__ invout,
                                                    int* __restrict__ ends,
                                                    int* __restrict__ bsums, int M) {
    __shared__ int tmp[256];
    int tid = threadIdx.x;
    int gid = blockIdx.x * 256 + tid;
    int cd = 0, cs = 0;
    if (gid < M) {
#pragma unroll 8
        for (int c = 0; c < ECH; c++) {
            cd += pdst[(size_t)c * BINS + gid];
            cs += psrc[(size_t)c * BINS + gid];
        }
        counts[gid] = cd;
        invin[gid]  = rsqrtf(fmaxf((float)cd, 1.0f));
        invout[gid] = rsqrtf(fmaxf((float)cs, 1.0f));
    }
    tmp[tid] = cd;
    __syncthreads();
    for (int off = 1; off < 256; off <<= 1) {
        int t = (tid >= off) ? tmp[tid - off] : 0;
        __syncthreads();
        tmp[tid] += t;
        __syncthreads();
    }
    if (gid < M) ends[gid] = tmp[tid];
    if (tid == 255) bsums[blockIdx.x] = tmp[255];
}

// ------- global scan finish + per-(chunk,bin) int cursors -> pcur -------
__global__ __launch_bounds__(256) void scan23_offs(int* __restrict__ ends,
                                                   const int* __restrict__ counts,
                                                   const int* __restrict__ bsums,
                                                   const unsigned short* __restrict__ pdst,
                                                   int* __restrict__ pcur, int nb, int M) {
    __shared__ int red[256];
    int tid = threadIdx.x;
    int b = blockIdx.x;
    red[tid] = (tid < b && tid < nb) ? bsums[tid] : 0;   // nb <= 256
    __syncthreads();
    for (int off = 128; off > 0; off >>= 1) {
        if (tid < off) red[tid] += red[tid + off];
        __syncthreads();
    }
    int prefix = red[0];
    int gid = b * 256 + tid;
    if (gid < M) {
        int e = ends[gid] + prefix;   // inclusive global end
        ends[gid] = e;
        int run = e - counts[gid];    // exclusive start
#pragma unroll 8
        for (int c = 0; c < ECH; c++) {
            size_t idx = (size_t)c * BINS + gid;
            int t = pdst[idx];
            pcur[idx] = run;
            run += t;
        }
    }
}

// ---------------- CSR fill via LDS cursors (int4 edge loads) ----------------
__global__ __launch_bounds__(BT) void fill_sorted(const int* __restrict__ src,
                                                  const int* __restrict__ dst,
                                                  const int* __restrict__ pcur,
                                                  int* __restrict__ csr_src, int nE) {
    __shared__ int cur[CHUNK];
    int c = blockIdx.x, n = blockIdx.y;
    int base = n * CHUNK;
    const int* o = pcur + (size_t)c * BINS + base;
    for (int i = threadIdx.x; i < CHUNK; i += BT) cur[i] = o[i];
    __syncthreads();
    int epc = (nE + ECH - 1) / ECH;
    int e0 = c * epc, e1 = min(e0 + epc, nE);
    int tid = threadIdx.x;
    int a0 = min((e0 + 3) & ~3, e1);
    if (tid < a0 - e0) {
        int e = e0 + tid;
        int d = dst[e] - base;
        if ((unsigned)d < (unsigned)CHUNK) csr_src[atomicAdd(&cur[d], 1)] = src[e];
    }
    int rem = e1 - a0;
    int nv = (rem > 0) ? (rem & ~3) : 0;
    for (int e = a0 + tid * 4; e < a0 + nv; e += BT * 4) {
        int4 d4 = *(const int4*)(dst + e);
        int4 s4 = *(const int4*)(src + e);
        int d;
        d = d4.x - base; if ((unsigned)d < (unsigned)CHUNK) csr_src[atomicAdd(&cur[d], 1)] = s4.x;
        d = d4.y - base; if ((unsigned)d < (unsigned)CHUNK) csr_src[atomicAdd(&cur[d], 1)] = s4.y;
        d = d4.z - base; if ((unsigned)d < (unsigned)CHUNK) csr_src[atomicAdd(&cur[d], 1)] = s4.z;
        d = d4.w - base; if ((unsigned)d < (unsigned)CHUNK) csr_src[atomicAdd(&cur[d], 1)] = s4.w;
    }
    int t0 = a0 + nv;
    if (tid < e1 - t0) {
        int e = t0 + tid;
        int d = dst[e] - base;
        if ((unsigned)d < (unsigned)CHUNK) csr_src[atomicAdd(&cur[d], 1)] = src[e];
    }
}

// ------- frontier via sorted-CSR ranges (global bitmap dedupe + ballot append) -------
__global__ __launch_bounds__(256) void frontier_csr(const int* __restrict__ list,
                                                    const int* __restrict__ cnt,
                                                    const int* __restrict__ ends,
                                                    const int* __restrict__ csr_src,
                                                    unsigned* __restrict__ bm_out,
                                                    int* __restrict__ out_list,
                                                    int* __restrict__ out_cnt) {
    int lane = threadIdx.x & 63;
    int wg = blockIdx.x * 4 + (threadIdx.x >> 6);
    int nW = gridDim.x * 4;
    int n = *cnt;
    for (int i = wg; i < n; i += nW) {
        int node = list[i];
        int end = ends[node];
        int beg = (node == 0) ? 0 : ends[node - 1];
        for (int e0 = beg; e0 < end; e0 += 64) {
            int u = 0;
            bool flag = false;
            if (e0 + lane < end) {
                u = csr_src[e0 + lane];
                unsigned old = atomicOr(&bm_out[u >> 5], 1u << (u & 31));
                flag = !((old >> (u & 31)) & 1);
            }
            unsigned long long mask = __ballot(flag);
            if (mask) {
                int leader = __ffsll((long long)mask) - 1;
                int base = 0;
                if (lane == leader) base = atomicAdd(out_cnt, __popcll(mask));
                base = __shfl(base, leader);
                if (flag) out_list[base + __popcll(mask & ((1ull << lane) - 1))] = u;
            }
        }
    }
}

// ---- fused layer: sorted-CSR gather + bf16 MFMA GEMM + invin/bias/LN/ReLU ----
// FP32IN: input rows are fp32 (features) scaled per-edge by edge_scale (invout)
template <int LAST, int FP32IN>
__global__ __launch_bounds__(256) void layer_fused(const void* __restrict__ FinV,
                                                   const float* __restrict__ edge_scale,
                                                   const int* __restrict__ ends,
                                                   const int* __restrict__ csr_src,
                                                   const short* __restrict__ Wt,
                                                   const float* __restrict__ invin,
                                                   const float* __restrict__ invout,
                                                   const float* __restrict__ bias,
                                                   const float* __restrict__ gamma,
                                                   const float* __restrict__ beta,
                                                   const int* __restrict__ list,
                                                   const int* __restrict__ cnt,
                                                   unsigned short* __restrict__ Fout,
                                                   float* __restrict__ out) {
    const unsigned* Fb = (const unsigned*)FinV;
    const float4*  Ff = (const float4*)FinV;
    __shared__ short As[16][136];
    __shared__ float sstat[2][4][16];
    __shared__ float sinv[2][16];
    __shared__ int snode[16];
    int tid = threadIdx.x;
    int w = tid >> 6, lane = tid & 63;
    int seg = lane >> 4, m = lane & 15;
    int n = *cnt;
    int tiles = (n + 15) >> 4;

    float bb[2], gg[2], pp[2];
#pragma unroll
    for (int j = 0; j < 2; j++) {
        int col = (w * 2 + j) * 16 + m;
        bb[j] = bias[col]; gg[j] = gamma[col]; pp[j] = beta[col];
    }

    for (int t = blockIdx.x; t < tiles; t += gridDim.x) {
        int base = t * 16;

        // ---- phase 1: gather 16 rows into LDS ----
        for (int q = 0; q < 4; q++) {
            int rr = w * 4 + q;
            int gr = base + rr;
            float ax[8];
#pragma unroll
            for (int k = 0; k < 8; k++) ax[k] = 0.f;
            int node = -1;
            if (gr < n) {
                node = list[gr];
                int end = ends[node];
                int e = (node == 0) ? 0 : ends[node - 1];
                while (e < end) {
                    int rem = end - e;
                    int myi = 0;
                    if (lane < rem) myi = csr_src[e + lane];
                    int nn = min(rem, 64);
                    int p = 0;
                    for (; p + 16 <= nn; p += 16) {
                        if (FP32IN) {
                            float4 fa[4], fb4[4]; float so[4];
#pragma unroll
                            for (int gi = 0; gi < 4; gi++) {
                                int idx = __shfl(myi, p + gi * 4 + seg);
                                so[gi] = edge_scale[idx];
                                const float4* qq = Ff + (size_t)idx * 32 + m * 2;
                                fa[gi] = qq[0]; fb4[gi] = qq[1];
                            }
#pragma unroll
                            for (int gi = 0; gi < 4; gi++) {
                                ax[0] += fa[gi].x * so[gi]; ax[1] += fa[gi].y * so[gi];
                                ax[2] += fa[gi].z * so[gi]; ax[3] += fa[gi].w * so[gi];
                                ax[4] += fb4[gi].x * so[gi]; ax[5] += fb4[gi].y * so[gi];
                                ax[6] += fb4[gi].z * so[gi]; ax[7] += fb4[gi].w * so[gi];
                            }
                        } else {
                            uint4 u[4];
#pragma unroll
                            for (int gi = 0; gi < 4; gi++) {
                                int idx = __shfl(myi, p + gi * 4 + seg);
                                u[gi] = *(const uint4*)(Fb + (size_t)idx * 64 + m * 4);
                            }
#pragma unroll
                            for (int gi = 0; gi < 4; gi++) {
                                ax[0] += __uint_as_float(u[gi].x << 16);
                                ax[1] += __uint_as_float(u[gi].x & 0xFFFF0000u);
                                ax[2] += __uint_as_float(u[gi].y << 16);
                                ax[3] += __uint_as_float(u[gi].y & 0xFFFF0000u);
                                ax[4] += __uint_as_float(u[gi].z << 16);
                                ax[5] += __uint_as_float(u[gi].z & 0xFFFF0000u);
                                ax[6] += __uint_as_float(u[gi].w << 16);
                                ax[7] += __uint_as_float(u[gi].w & 0xFFFF0000u);
                            }
                        }
                    }
                    for (; p < nn; p += 4) {
                        bool act = (p + seg) < nn;
                        int idx = __shfl(myi, (p + seg) & 63);
                        if (act) {
                            if (FP32IN) {
                                float so = edge_scale[idx];
                                const float4* qq = Ff + (size_t)idx * 32 + m * 2;
                                float4 fa = qq[0], fb4 = qq[1];
                                ax[0] += fa.x * so; ax[1] += fa.y * so;
                                ax[2] += fa.z * so; ax[3] += fa.w * so;
                                ax[4] += fb4.x * so; ax[5] += fb4.y * so;
                                ax[6] += fb4.z * so; ax[7] += fb4.w * so;
                            } else {
                                uint4 u = *(const uint4*)(Fb + (size_t)idx * 64 + m * 4);
                                ax[0] += __uint_as_float(u.x << 16);
                                ax[1] += __uint_as_float(u.x & 0xFFFF0000u);
                                ax[2] += __uint_as_float(u.y << 16);
                                ax[3] += __uint_as_float(u.y & 0xFFFF0000u);
                                ax[4] += __uint_as_float(u.z << 16);
                                ax[5] += __uint_as_float(u.z & 0xFFFF0000u);
                                ax[6] += __uint_as_float(u.w << 16);
                                ax[7] += __uint_as_float(u.w & 0xFFFF0000u);
                            }
                        }
                    }
                    e += nn;
                }
#pragma unroll
                for (int k = 0; k < 8; k++) {
                    ax[k] += __shfl_xor(ax[k], 16);
                    ax[k] += __shfl_xor(ax[k], 32);
                }
            }
            if (seg == 0) {   // lane m holds cols 8m..8m+7 of row rr
                uint4 o;
                o.x = (unsigned)f2bf(ax[0]) | ((unsigned)f2bf(ax[1]) << 16);
                o.y = (unsigned)f2bf(ax[2]) | ((unsigned)f2bf(ax[3]) << 16);
                o.z = (unsigned)f2bf(ax[4]) | ((unsigned)f2bf(ax[5]) << 16);
                o.w = (unsigned)f2bf(ax[6]) | ((unsigned)f2bf(ax[7]) << 16);
                *(uint4*)&As[rr][8 * m] = o;
            }
            if (lane == 0) {
                snode[rr] = node;
                sinv[0][rr] = (node >= 0) ? invin[node] : 1.f;
                sinv[1][rr] = (node >= 0) ? invout[node] : 1.f;
            }
        }
        __syncthreads();

        // ---- phase 2: MFMA (wave w covers cols w*32..w*32+31) ----
        short8 a[4];
#pragma unroll
        for (int k0 = 0; k0 < 4; k0++)
            a[k0] = *(const short8*)&As[m][k0 * 32 + seg * 8];
        v4f acc[2];
        acc[0] = (v4f){0.f, 0.f, 0.f, 0.f};
        acc[1] = (v4f){0.f, 0.f, 0.f, 0.f};
#pragma unroll
        for (int k0 = 0; k0 < 4; k0++) {
#pragma unroll
            for (int j = 0; j < 2; j++) {
                int ct = w * 2 + j;
                short8 b = *(const short8*)(Wt + (size_t)((k0 * 8 + ct) * 64 + lane) * 8);
                acc[j] = __builtin_amdgcn_mfma_f32_16x16x32_bf16(a[k0], b, acc[j], 0, 0, 0);
            }
        }

        float x[4][2];
#pragma unroll
        for (int r = 0; r < 4; r++) {
            int row = seg * 4 + r;
            float iv = sinv[0][row];
            float s = 0.f, sq = 0.f;
#pragma unroll
            for (int j = 0; j < 2; j++) {
                float c = acc[j][r] * iv + bb[j];
                x[r][j] = c;
                s += c; sq += c * c;
            }
#pragma unroll
            for (int off = 1; off < 16; off <<= 1) {
                s  += __shfl_xor(s, off);
                sq += __shfl_xor(sq, off);
            }
            if (m == 0) { sstat[0][w][row] = s; sstat[1][w][row] = sq; }
        }
        __syncthreads();

#pragma unroll
        for (int r = 0; r < 4; r++) {
            int row = seg * 4 + r;
            int gr = base + row;
            if (gr >= n) continue;
            float s  = sstat[0][0][row] + sstat[0][1][row] + sstat[0][2][row] + sstat[0][3][row];
            float sq = sstat[1][0][row] + sstat[1][1][row] + sstat[1][2][row] + sstat[1][3][row];
            float mu = s * (1.0f / RANK);
            float var = sq * (1.0f / RANK) - mu * mu;
            float rs = rsqrtf(var + LN_EPS);
#pragma unroll
            for (int j = 0; j < 2; j++) {
                int col = (w * 2 + j) * 16 + m;
                float y = fmaxf((x[r][j] - mu) * rs * gg[j] + pp[j], 0.f);
                if (LAST) {
                    out[(size_t)gr * RANK + col] = y;
                } else {
                    Fout[(size_t)snode[row] * RANK + col] = f2bf(y * sinv[1][row]);
                }
            }
        }
        __syncthreads();
    }
}

extern "C" void kernel_launch(void* const* d_in, const int* in_sizes, int n_in,
                              void* d_out, int out_size, void* d_ws, size_t ws_size,
                              hipStream_t stream) {
    const float* features = (const float*)d_in[0];
    const int* src = (const int*)d_in[1];
    const int* dst = (const int*)d_in[2];
    const int* bnn = (const int*)d_in[3];
    const float* Ws = (const float*)d_in[4];
    const float* bs = (const float*)d_in[5];
    const float* gammas = (const float*)d_in[6];
    const float* betas = (const float*)d_in[7];
    float* out = (float*)d_out;

    int M  = in_sizes[0] / RANK;   // 50000
    int nE = in_sizes[1];          // 640000
    int nG = in_sizes[3];          // 50
    int bmw = (M + 31) / 32;

    char* ws = (char*)d_ws;
    size_t off = 0;
    auto alloc = [&](size_t bytes) {
        void* p = ws + off;
        off += (bytes + 255) & ~(size_t)255;
        return p;
    };
    int*   counts  = (int*)alloc((size_t)M * 4);
    int*   ends    = (int*)alloc((size_t)M * 4);
    int*   bsums   = (int*)alloc(256 * 4);
    float* invout  = (float*)alloc((size_t)M * 4);
    float* invin   = (float*)alloc((size_t)M * 4);
    int*   csr_src = (int*)alloc((size_t)nE * 4);
    short* Wt      = (short*)alloc((size_t)3 * 16384 * 2);
    short* F1      = (short*)alloc((size_t)M * RANK * 2);
    short* F2      = (short*)alloc((size_t)M * RANK * 2);
    unsigned short* pdst = (unsigned short*)alloc((size_t)ECH * BINS * 2);  // 6.55 MB
    unsigned short* psrc = (unsigned short*)alloc((size_t)ECH * BINS * 2);  // 6.55 MB
    int*   pcur    = (int*)alloc((size_t)ECH * BINS * 4);                    // 13.1 MB
    // zeroed block: bm2 | bm1 | cnt2 | cnt1
    char*  zbase   = (char*)alloc((size_t)(2 * bmw + 2) * 4);
    unsigned* bm2  = (unsigned*)zbase;
    unsigned* bm1  = bm2 + bmw;
    int*   cnt2    = (int*)(bm1 + bmw);
    int*   cnt1    = cnt2 + 1;
    int*   cnt3    = (int*)alloc(256);
    int*   T3      = (int*)alloc((size_t)((nG + 63) & ~63) * 4);
    int*   T2      = (int*)alloc((size_t)M * 4);
    int*   T1      = (int*)alloc((size_t)M * 4);

    int nb = (M + 255) / 256;   // 196 <= 256 (required by scan23_offs)

    hipMemsetAsync(zbase, 0, (size_t)(2 * bmw + 2) * 4, stream);

    // ---- CSR build (4 kernels; hist also repacks W and inits T3 on spare blocks) ----
    hist_part<<<dim3(ECH + 1, NCH, 2), BT, 0, stream>>>(src, dst, pdst, psrc, Ws, Wt, nE,
                                                        bnn, nG, T3, cnt3);
    reduce_scan1<<<nb, 256, 0, stream>>>(pdst, psrc, counts, invin, invout, ends, bsums, M);
    scan23_offs<<<nb, 256, 0, stream>>>(ends, counts, bsums, pdst, pcur, nb, M);
    fill_sorted<<<dim3(ECH, NCH), BT, 0, stream>>>(src, dst, pcur, csr_src, nE);

    // ---- frontiers (2 parallel kernels; replaces serial mark_expand3) ----
    frontier_csr<<<64, 256, 0, stream>>>(T3, cnt3, ends, csr_src, bm2, T2, cnt2);
    frontier_csr<<<64, 256, 0, stream>>>(T2, cnt2, ends, csr_src, bm1, T1, cnt1);

    // ---- fused layers (3 kernels); L1 reads fp32 features w/ per-edge invout ----
    layer_fused<0, 1><<<512, 256, 0, stream>>>(features, invout, ends, csr_src, Wt,
                                               invin, invout, bs, gammas, betas,
                                               T1, cnt1, (unsigned short*)F1, nullptr);
    layer_fused<0, 0><<<64, 256, 0, stream>>>(F1, nullptr, ends, csr_src, Wt + 16384,
                                              invin, invout, bs + RANK, gammas + RANK, betas + RANK,
                                              T2, cnt2, (unsigned short*)F2, nullptr);
    layer_fused<1, 0><<<(nG + 15) / 16, 256, 0, stream>>>(F2, nullptr, ends, csr_src, Wt + 32768,
                                                          invin, invout, bs + 2 * RANK,
                                                          gammas + 2 * RANK, betas + 2 * RANK,
                                                          T3, cnt3, nullptr, out);
}